// Round 8
// baseline (165.579 us; speedup 1.0000x reference)
//
#include <hip/hip_runtime.h>
#include <hip/hip_bf16.h>

#define BATCH 2
#define SEQLEN 2048
#define DMODEL 256
#define DINNER 512
#define NHEADS 8
#define HEADDIM 64
#define DSTATE 64
#define CONVDIM 640
#define DINPROJ 1160
#define NTOK (BATCH*SEQLEN)
#define Q 64
#define NCH (SEQLEN/Q)
#define NPAD_IN 1216
#define TS 72          // bf16 MFMA tile stride
#define RS2 198        // raw conv-stage stride (word-stride 99, odd -> conflict-free)

typedef short v8s __attribute__((ext_vector_type(8)));
typedef float v4f __attribute__((ext_vector_type(4)));

__device__ __forceinline__ unsigned short f2bf(float f){
    __hip_bfloat16 h = __float2bfloat16(f);
    return *reinterpret_cast<unsigned short*>(&h);
}
__device__ __forceinline__ float bf2f(unsigned short u){
    unsigned int x = ((unsigned int)u) << 16;
    return __uint_as_float(x);
}

// ---------------- fused LayerNorm + in_proj MFMA GEMM (+ residual copy) ----------------
// grid (NTOK/128, NPAD_IN/64); 256 threads = 4 waves.
__global__ __launch_bounds__(256) void k_gemm_in(
        const float* __restrict__ hid, const float* __restrict__ nw, const float* __restrict__ nb,
        const float* __restrict__ Win, float* __restrict__ res, unsigned short* __restrict__ zxb){
    __shared__ __align__(16) unsigned short As[128*40];
    __shared__ __align__(16) unsigned short Bs[64*40];
    __shared__ float muS[128], rsS[128], nwS[256], nbS[256];
    int t = threadIdx.x;
    int lane = t & 63, w = t >> 6;
    int lanelow = lane & 15, quad = lane >> 4;
    int tok0 = blockIdx.x*128, n0 = blockIdx.y*64;
    nwS[t] = nw[t]; nbS[t] = nb[t];
    // LN stats: 2 threads per token
    {
        int j = t>>1, hf = t&1;
        const float* hp = hid + (size_t)(tok0+j)*DMODEL + hf*128;
        float sum=0.f, sq=0.f;
        #pragma unroll
        for(int i=0;i<32;i++){
            float4 v = *(const float4*)(hp + i*4);
            sum += v.x+v.y+v.z+v.w;
            sq  += v.x*v.x+v.y*v.y+v.z*v.z+v.w*v.w;
        }
        sum += __shfl_xor(sum,1); sq += __shfl_xor(sq,1);
        if(hf==0){
            float mu = sum*(1.f/256.f);
            float var = sq*(1.f/256.f) - mu*mu;
            muS[j] = mu; rsS[j] = rsqrtf(var + 1e-5f);
        }
    }
    // residual copy (one column-stripe only)
    if(blockIdx.y==0){
        const float4* hv = (const float4*)hid + (size_t)tok0*64;
        float4* rv = (float4*)res + (size_t)tok0*64;
        for(int i=0;i<32;i++) rv[i*256+t] = hv[i*256+t];
    }
    v4f acc[2][4];
    #pragma unroll
    for(int mi=0;mi<2;mi++)
        #pragma unroll
        for(int ni=0;ni<4;ni++)
            acc[mi][ni] = (v4f){0.f,0.f,0.f,0.f};
    __syncthreads();
    for(int k0=0; k0<DMODEL; k0+=32){
        if(k0) __syncthreads();
        // A-tile: LN-applied bf16 from hid
        #pragma unroll
        for(int cc=0; cc<2; cc++){
            int u = t + cc*256;
            int row = u>>2, off = u&3;
            const float* hp = hid + (size_t)(tok0+row)*DMODEL + k0 + off*8;
            float4 v0 = *(const float4*)hp;
            float4 v1 = *(const float4*)(hp+4);
            float mu = muS[row], rs = rsS[row];
            int cb = k0 + off*8;
            ushort4 lo, hi;
            lo.x = f2bf((v0.x-mu)*rs*nwS[cb+0] + nbS[cb+0]);
            lo.y = f2bf((v0.y-mu)*rs*nwS[cb+1] + nbS[cb+1]);
            lo.z = f2bf((v0.z-mu)*rs*nwS[cb+2] + nbS[cb+2]);
            lo.w = f2bf((v0.w-mu)*rs*nwS[cb+3] + nbS[cb+3]);
            hi.x = f2bf((v1.x-mu)*rs*nwS[cb+4] + nbS[cb+4]);
            hi.y = f2bf((v1.y-mu)*rs*nwS[cb+5] + nbS[cb+5]);
            hi.z = f2bf((v1.z-mu)*rs*nwS[cb+6] + nbS[cb+6]);
            hi.w = f2bf((v1.w-mu)*rs*nwS[cb+7] + nbS[cb+7]);
            *(ushort4*)&As[row*40 + off*8]     = lo;
            *(ushort4*)&As[row*40 + off*8 + 4] = hi;
        }
        // B-tile: on-the-fly Win fp32 -> bf16 transpose
        #pragma unroll
        for(int i=0;i<8;i++){
            int u = t + 256*i;
            int nl = u & 63, kl = u >> 6;
            int n = n0 + nl;
            float v = (n < DINPROJ) ? Win[(size_t)(k0+kl)*DINPROJ + n] : 0.f;
            Bs[nl*40 + kl] = f2bf(v);
        }
        __syncthreads();
        v8s a0 = *(const v8s*)&As[(w*32 +      lanelow)*40 + quad*8];
        v8s a1 = *(const v8s*)&As[(w*32 + 16 + lanelow)*40 + quad*8];
        v8s b[4];
        #pragma unroll
        for(int ni=0;ni<4;ni++)
            b[ni] = *(const v8s*)&Bs[(ni*16 + lanelow)*40 + quad*8];
        #pragma unroll
        for(int ni=0;ni<4;ni++){
            acc[0][ni] = __builtin_amdgcn_mfma_f32_16x16x32_bf16(a0, b[ni], acc[0][ni], 0,0,0);
            acc[1][ni] = __builtin_amdgcn_mfma_f32_16x16x32_bf16(a1, b[ni], acc[1][ni], 0,0,0);
        }
    }
    #pragma unroll
    for(int mi=0;mi<2;mi++){
        #pragma unroll
        for(int ni=0;ni<4;ni++){
            int col = n0 + ni*16 + lanelow;
            if(col < DINPROJ){
                #pragma unroll
                for(int r=0;r<4;r++){
                    int row = tok0 + w*32 + mi*16 + quad*4 + r;
                    zxb[(size_t)row*DINPROJ + col] = f2bf(acc[mi][ni][r]);
                }
            }
        }
    }
}

// ---------------- out-proj MFMA GEMM with on-the-fly Wout conversion ----------------
// grid (NTOK/128, DMODEL/64); 256 threads.
__global__ __launch_bounds__(256) void k_gemm_out(
        const unsigned short* __restrict__ Gb, const float* __restrict__ Wout,
        float* __restrict__ out){
    __shared__ __align__(16) unsigned short As[128*40];
    __shared__ __align__(16) unsigned short Bs[64*40];
    int t = threadIdx.x;
    int lane = t & 63, w = t >> 6;
    int lanelow = lane & 15, quad = lane >> 4;
    int tok0 = blockIdx.x * 128;
    int n0   = blockIdx.y * 64;
    v4f acc[2][4];
    #pragma unroll
    for(int mi=0;mi<2;mi++)
        #pragma unroll
        for(int ni=0;ni<4;ni++)
            acc[mi][ni] = (v4f){0.f,0.f,0.f,0.f};
    for(int k0=0; k0<DINNER; k0+=32){
        __syncthreads();
        #pragma unroll
        for(int cc=0; cc<2; cc++){
            int u = t + cc*256;
            int row = u>>2, off = u&3;
            uint4 v = *(const uint4*)(Gb + (size_t)(tok0+row)*DINNER + k0 + off*8);
            *(uint4*)&As[row*40 + off*8] = v;
        }
        #pragma unroll
        for(int i=0;i<8;i++){
            int u = t + 256*i;
            int nl = u & 63, kl = u >> 6;
            Bs[nl*40 + kl] = f2bf(Wout[(size_t)(k0+kl)*DMODEL + n0 + nl]);
        }
        __syncthreads();
        v8s a0 = *(const v8s*)&As[(w*32 +      lanelow)*40 + quad*8];
        v8s a1 = *(const v8s*)&As[(w*32 + 16 + lanelow)*40 + quad*8];
        v8s b[4];
        #pragma unroll
        for(int ni=0;ni<4;ni++)
            b[ni] = *(const v8s*)&Bs[(ni*16 + lanelow)*40 + quad*8];
        #pragma unroll
        for(int ni=0;ni<4;ni++){
            acc[0][ni] = __builtin_amdgcn_mfma_f32_16x16x32_bf16(a0, b[ni], acc[0][ni], 0,0,0);
            acc[1][ni] = __builtin_amdgcn_mfma_f32_16x16x32_bf16(a1, b[ni], acc[1][ni], 0,0,0);
        }
    }
    #pragma unroll
    for(int mi=0;mi<2;mi++){
        #pragma unroll
        for(int ni=0;ni<4;ni++){
            int col = n0 + ni*16 + lanelow;
            #pragma unroll
            for(int r=0;r<4;r++){
                int row = tok0 + w*32 + mi*16 + quad*4 + r;
                out[(size_t)row*DMODEL + col] = acc[mi][ni][r];
            }
        }
    }
}

// ---------------- fused conv + chunk-local SSD via MFMA (bf16 in/out) ----------------
__global__ __launch_bounds__(256) void k_chunk1(
        const unsigned short* __restrict__ zxb, const float* __restrict__ conv_w, const float* __restrict__ conv_b,
        const float* __restrict__ dt_bias, const float* __restrict__ A_log, const float* __restrict__ D_param,
        unsigned short* __restrict__ yw16, float* __restrict__ contrib,
        float* __restrict__ Larr, float* __restrict__ decayArr, unsigned short* __restrict__ Ccv){
    int blk = blockIdx.x;
    int c = blk & 31, h = (blk>>5)&7, b = blk>>8;
    int t = threadIdx.x;
    int lane = t & 63, w = t >> 6;
    int lanelow = lane & 15, quad = lane >> 4;
    __shared__ __align__(16) unsigned short raw[67*RS2];
    __shared__ __align__(16) unsigned short Cb[64*TS];
    __shared__ __align__(16) unsigned short Bb[64*TS];
    __shared__ __align__(16) unsigned short BtW[64*TS];
    __shared__ __align__(16) unsigned short Xt[64*TS];
    __shared__ float Ls[Q], dts[Q], wch[Q];
    unsigned short* Gbuf = raw;
    int l0 = c*Q;
    int bh = b*NHEADS + h;
    const unsigned short* zbase = zxb + (size_t)(b*SEQLEN + l0)*DINPROJ;
    for(int i=0;i<7;i++){
        int gidx = t + 256*i;
        if(gidx < 67*24){
            int row = gidx/24, g = gidx%24;
            int ltok = l0 - 3 + row;
            int gcol = (g<8) ? (DINNER + h*HEADDIM + g*8) : (2*DINNER + (g-8)*8);
            uint4 v;
            if(ltok >= 0) v = *(const uint4*)(zbase + (ptrdiff_t)(row-3)*DINPROJ + gcol);
            else { v.x=0; v.y=0; v.z=0; v.w=0; }
            int ch = (g<8) ? g*8 : 64 + (g-8)*8;
            unsigned int* d = (unsigned int*)&raw[row*RS2 + ch];
            d[0]=v.x; d[1]=v.y; d[2]=v.z; d[3]=v.w;
        }
    }
    if(t < Q){
        float v = bf2f(zbase[(size_t)t*DINPROJ + (DINPROJ-NHEADS) + h]) + dt_bias[h];
        float dt = (v > 20.f) ? v : log1pf(__expf(v));
        float A  = -__expf(A_log[h]);
        float ld = dt*A;
        #pragma unroll
        for(int off=1; off<64; off<<=1){
            float u = __shfl_up(ld, off);
            if(lane >= off) ld += u;
        }
        Ls[t] = ld; dts[t] = dt;
    }
    __syncthreads();
    float L63 = Ls[Q-1];
    if(t < Q) wch[t] = __expf(L63 - Ls[t]) * dts[t];
    __syncthreads();
    unsigned short* CcP = Ccv + ((size_t)b*NCH + c)*4096;
    for(int i=0;i<12;i++){
        int u = t + 256*i;
        int st = u & 63, c4 = u >> 6, ch = c4*4;
        float xk[4][4];
        #pragma unroll
        for(int k=0;k<4;k++){
            const unsigned short* rp = &raw[(st+k)*RS2 + ch];
            ushort2 p0 = *(const ushort2*)rp;
            ushort2 p1 = *(const ushort2*)(rp+2);
            xk[k][0]=bf2f(p0.x); xk[k][1]=bf2f(p0.y); xk[k][2]=bf2f(p1.x); xk[k][3]=bf2f(p1.y);
        }
        float wst = wch[st];
        #pragma unroll
        for(int j=0;j<4;j++){
            int chj = ch+j;
            int cc = (chj<64) ? (h*HEADDIM + chj) : (448 + chj);
            float4 wv = *(const float4*)&conv_w[cc*4];
            float acc = conv_b[cc] + wv.x*xk[0][j] + wv.y*xk[1][j] + wv.z*xk[2][j] + wv.w*xk[3][j];
            float sv = acc/(1.f+__expf(-acc));
            if(chj < 64){
                Xt[chj*TS + st] = f2bf(sv);
            } else if(chj < 128){
                int n = chj-64;
                Bb[st*TS + n]  = f2bf(sv);
                BtW[n*TS + st] = f2bf(sv*wst);
            } else {
                int n = chj-128;
                unsigned short sb = f2bf(sv);
                Cb[st*TS + n] = sb;
                if(h==0) CcP[st*64 + n] = sb;
            }
        }
    }
    __syncthreads();
    v4f g[4];
    #pragma unroll
    for(int nt=0;nt<4;nt++) g[nt] = (v4f){0.f,0.f,0.f,0.f};
    #pragma unroll
    for(int kk=0;kk<2;kk++){
        v8s a = *(const v8s*)&Cb[(w*16+lanelow)*TS + kk*32 + quad*8];
        #pragma unroll
        for(int nt=0;nt<4;nt++){
            v8s bb = *(const v8s*)&Bb[(nt*16+lanelow)*TS + kk*32 + quad*8];
            g[nt] = __builtin_amdgcn_mfma_f32_16x16x32_bf16(a, bb, g[nt], 0,0,0);
        }
    }
    float Lrow[4];
    #pragma unroll
    for(int r=0;r<4;r++) Lrow[r] = Ls[w*16 + quad*4 + r];
    #pragma unroll
    for(int nt=0;nt<4;nt++){
        int col = nt*16 + lanelow;
        float Lc = Ls[col], dtc = dts[col];
        #pragma unroll
        for(int r=0;r<4;r++){
            int rowg = w*16 + quad*4 + r;
            float val = (col <= rowg) ? g[nt][r] * __expf(Lrow[r]-Lc) * dtc : 0.f;
            Gbuf[rowg*TS + col] = f2bf(val);
        }
    }
    __syncthreads();
    v4f ya[4], sa[4];
    #pragma unroll
    for(int nt=0;nt<4;nt++){ ya[nt]=(v4f){0.f,0.f,0.f,0.f}; sa[nt]=(v4f){0.f,0.f,0.f,0.f}; }
    #pragma unroll
    for(int kk=0;kk<2;kk++){
        v8s ag = *(const v8s*)&Gbuf[(w*16+lanelow)*TS + kk*32 + quad*8];
        v8s ax = *(const v8s*)&Xt[(w*16+lanelow)*TS + kk*32 + quad*8];
        #pragma unroll
        for(int nt=0;nt<4;nt++){
            v8s bx = *(const v8s*)&Xt[(nt*16+lanelow)*TS + kk*32 + quad*8];
            v8s bw = *(const v8s*)&BtW[(nt*16+lanelow)*TS + kk*32 + quad*8];
            ya[nt] = __builtin_amdgcn_mfma_f32_16x16x32_bf16(ag, bx, ya[nt], 0,0,0);
            sa[nt] = __builtin_amdgcn_mfma_f32_16x16x32_bf16(ax, bw, sa[nt], 0,0,0);
        }
    }
    float Dp = D_param[h];
    #pragma unroll
    for(int nt=0;nt<4;nt++){
        int col = nt*16 + lanelow;
        #pragma unroll
        for(int r=0;r<4;r++){
            int i = w*16 + quad*4 + r;
            float xval = bf2f(Xt[col*TS + i]);
            yw16[((size_t)b*SEQLEN + l0 + i)*DINNER + h*HEADDIM + col] = f2bf(ya[nt][r] + Dp*xval);
            contrib[(((size_t)bh*NCH + c)*64 + i)*64 + col] = sa[nt][r];
        }
    }
    if(t < Q) Larr[((size_t)bh*NCH + c)*Q + t] = Ls[t];
    if(t == 0) decayArr[bh*NCH + c] = __expf(L63);
}

// ---------------- inter-chunk state scan ----------------
__global__ __launch_bounds__(256) void k_chunk2(const float* __restrict__ contrib,
                                                const float* __restrict__ decayArr,
                                                unsigned short* __restrict__ Sb){
    int bh = blockIdx.x >> 4;
    int part = blockIdx.x & 15;
    int e = part*256 + threadIdx.x;
    const size_t base = (size_t)bh*NCH*4096 + e;
    float vals[NCH];
    #pragma unroll
    for(int c=0;c<NCH;c++) vals[c] = contrib[base + (size_t)c*4096];
    float s = 0.f;
    #pragma unroll
    for(int c=0;c<NCH;c++){
        Sb[base + (size_t)c*4096] = f2bf(s);
        s = fmaf(s, decayArr[bh*NCH + c], vals[c]);
    }
}

// ---------------- fused inter-chunk output + gate + RMSNorm -> bf16 G ----------------
__global__ __launch_bounds__(512) void k_tail(
        const unsigned short* __restrict__ Ccv, const unsigned short* __restrict__ Sb,
        const float* __restrict__ Larr, const unsigned short* __restrict__ yw16,
        const unsigned short* __restrict__ zxb, const float* __restrict__ rms_w,
        unsigned short* __restrict__ Gb){
    int blk = blockIdx.x;
    int c = blk & 31, b = blk >> 5;
    int t = threadIdx.x;
    int h = t >> 6, lane = t & 63;
    int lanelow = lane & 15, quad = lane >> 4;
    int bh = b*NHEADS + h;
    __shared__ float wsum[8][64];
    __shared__ float rstdS[64];
    const unsigned short* Cp = Ccv + ((size_t)b*NCH + c)*4096;
    const unsigned short* Sp = Sb + ((size_t)bh*NCH + c)*4096;
    v8s a[4][2];
    #pragma unroll
    for(int rt=0;rt<4;rt++){
        a[rt][0] = *(const v8s*)(Cp + (rt*16+lanelow)*64 + quad*8);
        a[rt][1] = *(const v8s*)(Cp + (rt*16+lanelow)*64 + 32 + quad*8);
    }
    v8s s[4][2];
    #pragma unroll
    for(int nt=0;nt<4;nt++){
        s[nt][0] = *(const v8s*)(Sp + (nt*16+lanelow)*64 + quad*8);
        s[nt][1] = *(const v8s*)(Sp + (nt*16+lanelow)*64 + 32 + quad*8);
    }
    float g[4][4][4];
    float sq[4][4];
    const float* Lp = Larr + ((size_t)bh*NCH + c)*Q;
    #pragma unroll
    for(int rt=0;rt<4;rt++){
        float eL[4];
        #pragma unroll
        for(int r=0;r<4;r++) eL[r] = __expf(Lp[rt*16 + quad*4 + r]);
        #pragma unroll
        for(int nt=0;nt<4;nt++){
            v4f acc = (v4f){0.f,0.f,0.f,0.f};
            acc = __builtin_amdgcn_mfma_f32_16x16x32_bf16(a[rt][0], s[nt][0], acc, 0,0,0);
            acc = __builtin_amdgcn_mfma_f32_16x16x32_bf16(a[rt][1], s[nt][1], acc, 0,0,0);
            int col = h*HEADDIM + nt*16 + lanelow;
            #pragma unroll
            for(int r=0;r<4;r++){
                int i = rt*16 + quad*4 + r;
                size_t tok = (size_t)b*SEQLEN + c*Q + i;
                float yv = acc[r]*eL[r] + bf2f(yw16[tok*DINNER + col]);
                float z  = bf2f(zxb[tok*DINPROJ + col]);
                float gg = yv * (z/(1.f+__expf(-z)));
                g[rt][nt][r] = gg;
                sq[rt][r] = (nt==0 ? gg*gg : sq[rt][r] + gg*gg);
            }
        }
    }
    #pragma unroll
    for(int rt=0;rt<4;rt++)
        #pragma unroll
        for(int r=0;r<4;r++){
            float v = sq[rt][r];
            #pragma unroll
            for(int m=1;m<16;m<<=1) v += __shfl_xor(v, m);
            sq[rt][r] = v;
        }
    if(lanelow==0){
        #pragma unroll
        for(int rt=0;rt<4;rt++)
            #pragma unroll
            for(int r=0;r<4;r++)
                wsum[h][rt*16 + quad*4 + r] = sq[rt][r];
    }
    __syncthreads();
    if(t < 64){
        float tot = 0.f;
        #pragma unroll
        for(int hh=0;hh<8;hh++) tot += wsum[hh][t];
        rstdS[t] = rsqrtf(tot*(1.f/512.f) + 1e-5f);
    }
    __syncthreads();
    #pragma unroll
    for(int rt=0;rt<4;rt++){
        #pragma unroll
        for(int nt=0;nt<4;nt++){
            int col = h*HEADDIM + nt*16 + lanelow;
            float rw = rms_w[col];
            #pragma unroll
            for(int r=0;r<4;r++){
                int i = rt*16 + quad*4 + r;
                Gb[((size_t)b*SEQLEN + c*Q + i)*DINNER + col] = f2bf(g[rt][nt][r] * rstdS[i] * rw);
            }
        }
    }
}

extern "C" void kernel_launch(void* const* d_in, const int* in_sizes, int n_in,
                              void* d_out, int out_size, void* d_ws, size_t ws_size,
                              hipStream_t stream) {
    const float* hid     = (const float*)d_in[0];
    const float* norm_w  = (const float*)d_in[1];
    const float* norm_b  = (const float*)d_in[2];
    const float* Win     = (const float*)d_in[3];
    const float* conv_w  = (const float*)d_in[4];
    const float* conv_b  = (const float*)d_in[5];
    const float* dt_bias = (const float*)d_in[6];
    const float* A_log   = (const float*)d_in[7];
    const float* D_param = (const float*)d_in[8];
    const float* rms_w   = (const float*)d_in[9];
    const float* Wout    = (const float*)d_in[10];

    float* ws = (float*)d_ws;
    float* contrib = ws;                                          // 16*32*4096 f
    float* Larr    = contrib + (size_t)16*NCH*4096;               // 32768 f
    float* decayA  = Larr + (size_t)16*NCH*Q;                     // 512 f
    unsigned short* zxb  = (unsigned short*)(decayA + 512);       // 4096*1160
    unsigned short* yw16 = zxb + (size_t)NTOK*DINPROJ;            // 4096*512
    unsigned short* Sb   = yw16 + (size_t)NTOK*DINNER;            // 16*32*4096
    unsigned short* Ccv  = Sb + (size_t)16*NCH*4096;              // 2*32*4096
    unsigned short* Gb   = Ccv + (size_t)BATCH*NCH*4096;          // 4096*512

    float* out = (float*)d_out;
    float* res = out + (size_t)NTOK*DMODEL;

    k_gemm_in<<<dim3(NTOK/128, NPAD_IN/64), 256, 0, stream>>>(hid, norm_w, norm_b, Win, res, zxb);
    k_chunk1<<<BATCH*NHEADS*NCH, 256, 0, stream>>>(zxb, conv_w, conv_b, dt_bias, A_log, D_param,
                                                   yw16, contrib, Larr, decayA, Ccv);
    k_chunk2<<<256, 256, 0, stream>>>(contrib, decayA, Sb);
    k_tail<<<BATCH*NCH, 512, 0, stream>>>(Ccv, Sb, Larr, yw16, zxb, rms_w, Gb);
    k_gemm_out<<<dim3(NTOK/128, DMODEL/64), 256, 0, stream>>>(Gb, Wout, out);
}

// Round 9
// 146.297 us; speedup vs baseline: 1.1318x; 1.1318x over previous
//
#include <hip/hip_runtime.h>
#include <hip/hip_bf16.h>

#define BATCH 2
#define SEQLEN 2048
#define DMODEL 256
#define DINNER 512
#define NHEADS 8
#define HEADDIM 64
#define DSTATE 64
#define CONVDIM 640
#define DINPROJ 1160
#define NTOK (BATCH*SEQLEN)
#define Q 64
#define NCH (SEQLEN/Q)
#define NPAD_IN 1216
#define TS 72          // bf16 MFMA tile stride

typedef short v8s __attribute__((ext_vector_type(8)));
typedef float v4f __attribute__((ext_vector_type(4)));

__device__ __forceinline__ unsigned short f2bf(float f){
    __hip_bfloat16 h = __float2bfloat16(f);
    return *reinterpret_cast<unsigned short*>(&h);
}
__device__ __forceinline__ float bf2f(unsigned short u){
    unsigned int x = ((unsigned int)u) << 16;
    return __uint_as_float(x);
}

// ---------------- prep: LayerNorm (+residual) and weight conversion, block-partitioned ----------------
// grid 624 = 256 (LN) + 304 (Win cvt) + 64 (Wout cvt)
__global__ __launch_bounds__(256) void k_prep(
        const float* __restrict__ hid, const float* __restrict__ nw, const float* __restrict__ nb,
        const float* __restrict__ Win, const float* __restrict__ Wout,
        float* __restrict__ res, unsigned short* __restrict__ Xb,
        unsigned short* __restrict__ Wti, unsigned short* __restrict__ Wto){
    int bx = blockIdx.x;
    int t = threadIdx.x;
    if(bx < 256){
        __shared__ float xs[16][DMODEL];
        int tok0 = bx*16;
        for(int i=0;i<16;i++){
            int idx = i*256+t; int j = idx>>8, c = idx&255;
            float v = hid[(size_t)(tok0+j)*DMODEL + c];
            xs[j][c] = v;
            res[(size_t)(tok0+j)*DMODEL + c] = v;
        }
        __syncthreads();
        int g = t>>4, il = t&15;
        float sum=0.f, sumsq=0.f;
        for(int i=0;i<16;i++){ float v = xs[g][il*16+i]; sum += v; sumsq += v*v; }
        #pragma unroll
        for(int m=1;m<16;m<<=1){ sum += __shfl_xor(sum,m); sumsq += __shfl_xor(sumsq,m); }
        float mu   = sum*(1.f/256.f);
        float var  = sumsq*(1.f/256.f) - mu*mu;
        float rstd = rsqrtf(var + 1e-5f);
        for(int i=0;i<16;i++){
            int c = il*16+i;
            xs[g][c] = (xs[g][c]-mu)*rstd*nw[c] + nb[c];
        }
        __syncthreads();
        for(int i=0;i<16;i++){
            int idx = i*256+t; int j = idx>>8, c = idx&255;
            Xb[(size_t)(tok0+j)*DMODEL + c] = f2bf(xs[j][c]);
        }
    } else if(bx < 256 + NPAD_IN/4){
        int n0 = (bx-256)*4, k = t;
        #pragma unroll
        for(int i=0;i<4;i++){
            int n = n0+i;
            float v = (n < DINPROJ) ? Win[(size_t)k*DINPROJ + n] : 0.f;
            Wti[(size_t)n*DMODEL + k] = f2bf(v);
        }
    } else {
        int n0 = (bx - 256 - NPAD_IN/4)*4;
        #pragma unroll
        for(int kk=0;kk<2;kk++){
            int k = t + kk*256;
            #pragma unroll
            for(int i=0;i<4;i++){
                int n = n0+i;
                Wto[(size_t)n*DINNER + k] = f2bf(Wout[(size_t)k*DMODEL + n]);
            }
        }
    }
}

// ---------------- MFMA bf16 GEMM: C(MxN) = A(MxK,bf16) @ Bt(NxK,bf16)^T ----------------
template<int BF16OUT>
__global__ __launch_bounds__(256) void k_gemm(
        const unsigned short* __restrict__ A, const unsigned short* __restrict__ Bt,
        float* __restrict__ Cf, unsigned short* __restrict__ Cb, int K, int Ncols){
    __shared__ __align__(16) unsigned short As[128*40];
    __shared__ __align__(16) unsigned short Bs[64*40];
    int t = threadIdx.x;
    int lane = t & 63, w = t >> 6;
    int lanelow = lane & 15, quad = lane >> 4;
    int tok0 = blockIdx.x * 128;
    int n0   = blockIdx.y * 64;
    v4f acc[2][4];
    #pragma unroll
    for(int mi=0;mi<2;mi++)
        #pragma unroll
        for(int ni=0;ni<4;ni++)
            acc[mi][ni] = (v4f){0.f,0.f,0.f,0.f};
    for(int k0=0; k0<K; k0+=32){
        __syncthreads();
        #pragma unroll
        for(int cc=0; cc<2; cc++){
            int c = t + cc*256;
            int row = c>>2, off = c&3;
            uint4 v = *(const uint4*)(A + (size_t)(tok0+row)*K + k0 + off*8);
            *(uint4*)&As[row*40 + off*8] = v;
        }
        {
            int row = t>>2, off = t&3;
            uint4 v = *(const uint4*)(Bt + (size_t)(n0+row)*K + k0 + off*8);
            *(uint4*)&Bs[row*40 + off*8] = v;
        }
        __syncthreads();
        v8s a0 = *(const v8s*)&As[(w*32 +      lanelow)*40 + quad*8];
        v8s a1 = *(const v8s*)&As[(w*32 + 16 + lanelow)*40 + quad*8];
        v8s b[4];
        #pragma unroll
        for(int ni=0;ni<4;ni++)
            b[ni] = *(const v8s*)&Bs[(ni*16 + lanelow)*40 + quad*8];
        #pragma unroll
        for(int ni=0;ni<4;ni++){
            acc[0][ni] = __builtin_amdgcn_mfma_f32_16x16x32_bf16(a0, b[ni], acc[0][ni], 0,0,0);
            acc[1][ni] = __builtin_amdgcn_mfma_f32_16x16x32_bf16(a1, b[ni], acc[1][ni], 0,0,0);
        }
    }
    #pragma unroll
    for(int mi=0;mi<2;mi++){
        #pragma unroll
        for(int ni=0;ni<4;ni++){
            int col = n0 + ni*16 + lanelow;
            if(col < Ncols){
                #pragma unroll
                for(int r=0;r<4;r++){
                    int row = tok0 + w*32 + mi*16 + quad*4 + r;
                    if(BF16OUT) Cb[(size_t)row*Ncols + col] = f2bf(acc[mi][ni][r]);
                    else        Cf[(size_t)row*Ncols + col] = acc[mi][ni][r];
                }
            }
        }
    }
}

// ---------------- fused conv + chunk-local SSD via MFMA; conv reads global (L1/L2-hot) ----------------
// grid 512 = b x h x chunk; 256 threads = 4 waves.  LDS ~46.8 KB -> 3 blocks/CU.
__global__ __launch_bounds__(256) void k_chunk1(
        const unsigned short* __restrict__ zxb, const float* __restrict__ conv_w, const float* __restrict__ conv_b,
        const float* __restrict__ dt_bias, const float* __restrict__ A_log, const float* __restrict__ D_param,
        unsigned short* __restrict__ yw16, float* __restrict__ contrib,
        float* __restrict__ Larr, float* __restrict__ decayArr, unsigned short* __restrict__ Ccv){
    int blk = blockIdx.x;
    int c = blk & 31, h = (blk>>5)&7, b = blk>>8;
    int t = threadIdx.x;
    int lane = t & 63, w = t >> 6;
    int lanelow = lane & 15, quad = lane >> 4;
    __shared__ __align__(16) unsigned short Cb[64*TS];
    __shared__ __align__(16) unsigned short Bb[64*TS];
    __shared__ __align__(16) unsigned short BtW[64*TS];
    __shared__ __align__(16) unsigned short Xt[64*TS];
    __shared__ __align__(16) unsigned short Gbuf[64*TS];
    __shared__ float Ls[Q], dts[Q], wch[Q];
    int l0 = c*Q;
    int bh = b*NHEADS + h;
    const unsigned short* zbase = zxb + (size_t)(b*SEQLEN + l0)*DINPROJ;
    // ---- dt softplus + ldA cumsum (wave 0) ----
    if(t < Q){
        float v = bf2f(zbase[(size_t)t*DINPROJ + (DINPROJ-NHEADS) + h]) + dt_bias[h];
        float dt = (v > 20.f) ? v : log1pf(__expf(v));
        float A  = -__expf(A_log[h]);
        float ld = dt*A;
        #pragma unroll
        for(int off=1; off<64; off<<=1){
            float u = __shfl_up(ld, off);
            if(lane >= off) ld += u;
        }
        Ls[t] = ld; dts[t] = dt;
    }
    __syncthreads();
    float L63 = Ls[Q-1];
    if(t < Q) wch[t] = __expf(L63 - Ls[t]) * dts[t];
    __syncthreads();
    // ---- conv(K=4) + SiLU directly from global -> MFMA tiles ----
    unsigned short* CcP = Ccv + ((size_t)b*NCH + c)*4096;
    for(int i=0;i<12;i++){
        int u = t + 256*i;           // 3072 units = 48 ch-groups(4ch) x 64 rows
        int st = u & 63, c4 = u >> 6, ch = c4*4;
        int gcol = (ch < 64) ? (DINNER + h*HEADDIM + ch) : (2*DINNER + (ch-64));
        const unsigned short* colp = zbase + (ptrdiff_t)st*DINPROJ + gcol;
        float xk[4][4];
        #pragma unroll
        for(int k=0;k<4;k++){
            int l = l0 + st + k - 3;
            ushort4 v;
            if(l >= 0) v = *(const ushort4*)(colp - (ptrdiff_t)(3-k)*DINPROJ);
            else { v.x=0; v.y=0; v.z=0; v.w=0; }
            xk[k][0]=bf2f(v.x); xk[k][1]=bf2f(v.y); xk[k][2]=bf2f(v.z); xk[k][3]=bf2f(v.w);
        }
        float wst = wch[st];
        #pragma unroll
        for(int j=0;j<4;j++){
            int chj = ch+j;
            int cc = (chj<64) ? (h*HEADDIM + chj) : (448 + chj);
            float4 wv = *(const float4*)&conv_w[cc*4];
            float acc = conv_b[cc] + wv.x*xk[0][j] + wv.y*xk[1][j] + wv.z*xk[2][j] + wv.w*xk[3][j];
            float sv = acc/(1.f+__expf(-acc));
            if(chj < 64){
                Xt[chj*TS + st] = f2bf(sv);
            } else if(chj < 128){
                int n = chj-64;
                Bb[st*TS + n]  = f2bf(sv);
                BtW[n*TS + st] = f2bf(sv*wst);
            } else {
                int n = chj-128;
                unsigned short sb = f2bf(sv);
                Cb[st*TS + n] = sb;
                if(h==0) CcP[st*64 + n] = sb;
            }
        }
    }
    __syncthreads();
    // ---- G = C.B^T ----
    v4f g[4];
    #pragma unroll
    for(int nt=0;nt<4;nt++) g[nt] = (v4f){0.f,0.f,0.f,0.f};
    #pragma unroll
    for(int kk=0;kk<2;kk++){
        v8s a = *(const v8s*)&Cb[(w*16+lanelow)*TS + kk*32 + quad*8];
        #pragma unroll
        for(int nt=0;nt<4;nt++){
            v8s bb = *(const v8s*)&Bb[(nt*16+lanelow)*TS + kk*32 + quad*8];
            g[nt] = __builtin_amdgcn_mfma_f32_16x16x32_bf16(a, bb, g[nt], 0,0,0);
        }
    }
    float Lrow[4];
    #pragma unroll
    for(int r=0;r<4;r++) Lrow[r] = Ls[w*16 + quad*4 + r];
    #pragma unroll
    for(int nt=0;nt<4;nt++){
        int col = nt*16 + lanelow;
        float Lc = Ls[col], dtc = dts[col];
        #pragma unroll
        for(int r=0;r<4;r++){
            int rowg = w*16 + quad*4 + r;
            float val = (col <= rowg) ? g[nt][r] * __expf(Lrow[r]-Lc) * dtc : 0.f;
            Gbuf[rowg*TS + col] = f2bf(val);
        }
    }
    __syncthreads();
    // ---- Y = G.X ; S = (X^T).(BtW^T) ----
    v4f ya[4], sa[4];
    #pragma unroll
    for(int nt=0;nt<4;nt++){ ya[nt]=(v4f){0.f,0.f,0.f,0.f}; sa[nt]=(v4f){0.f,0.f,0.f,0.f}; }
    #pragma unroll
    for(int kk=0;kk<2;kk++){
        v8s ag = *(const v8s*)&Gbuf[(w*16+lanelow)*TS + kk*32 + quad*8];
        v8s ax = *(const v8s*)&Xt[(w*16+lanelow)*TS + kk*32 + quad*8];
        #pragma unroll
        for(int nt=0;nt<4;nt++){
            v8s bx = *(const v8s*)&Xt[(nt*16+lanelow)*TS + kk*32 + quad*8];
            v8s bw = *(const v8s*)&BtW[(nt*16+lanelow)*TS + kk*32 + quad*8];
            ya[nt] = __builtin_amdgcn_mfma_f32_16x16x32_bf16(ag, bx, ya[nt], 0,0,0);
            sa[nt] = __builtin_amdgcn_mfma_f32_16x16x32_bf16(ax, bw, sa[nt], 0,0,0);
        }
    }
    float Dp = D_param[h];
    #pragma unroll
    for(int nt=0;nt<4;nt++){
        int col = nt*16 + lanelow;
        #pragma unroll
        for(int r=0;r<4;r++){
            int i = w*16 + quad*4 + r;
            float xval = bf2f(Xt[col*TS + i]);
            yw16[((size_t)b*SEQLEN + l0 + i)*DINNER + h*HEADDIM + col] = f2bf(ya[nt][r] + Dp*xval);
            contrib[(((size_t)bh*NCH + c)*64 + i)*64 + col] = sa[nt][r];
        }
    }
    if(t < Q) Larr[((size_t)bh*NCH + c)*Q + t] = Ls[t];
    if(t == 0) decayArr[bh*NCH + c] = __expf(L63);
}

// ---------------- inter-chunk state scan ----------------
__global__ __launch_bounds__(256) void k_chunk2(const float* __restrict__ contrib,
                                                const float* __restrict__ decayArr,
                                                unsigned short* __restrict__ Sb){
    int bh = blockIdx.x >> 4;
    int part = blockIdx.x & 15;
    int e = part*256 + threadIdx.x;
    const size_t base = (size_t)bh*NCH*4096 + e;
    float vals[NCH];
    #pragma unroll
    for(int c=0;c<NCH;c++) vals[c] = contrib[base + (size_t)c*4096];
    float s = 0.f;
    #pragma unroll
    for(int c=0;c<NCH;c++){
        Sb[base + (size_t)c*4096] = f2bf(s);
        s = fmaf(s, decayArr[bh*NCH + c], vals[c]);
    }
}

// ---------------- fused inter-chunk output + gate + RMSNorm -> bf16 G ----------------
// grid 128 = b(2) x chunk(32) x half(2); 512 threads = 8 waves, wave = head; 32 tokens/block.
__global__ __launch_bounds__(512) void k_tail(
        const unsigned short* __restrict__ Ccv, const unsigned short* __restrict__ Sb,
        const float* __restrict__ Larr, const unsigned short* __restrict__ yw16,
        const unsigned short* __restrict__ zxb, const float* __restrict__ rms_w,
        unsigned short* __restrict__ Gb){
    int blk = blockIdx.x;
    int half = blk & 1, c = (blk>>1) & 31, b = blk >> 6;
    int t = threadIdx.x;
    int h = t >> 6, lane = t & 63;
    int lanelow = lane & 15, quad = lane >> 4;
    int bh = b*NHEADS + h;
    __shared__ float wsum[8][32];
    __shared__ float rstdS[32];
    const unsigned short* Cp = Ccv + ((size_t)b*NCH + c)*4096;
    const unsigned short* Sp = Sb + ((size_t)bh*NCH + c)*4096;
    v8s a[2][2];
    #pragma unroll
    for(int rt=0;rt<2;rt++){
        int row = half*32 + rt*16 + lanelow;
        a[rt][0] = *(const v8s*)(Cp + row*64 + quad*8);
        a[rt][1] = *(const v8s*)(Cp + row*64 + 32 + quad*8);
    }
    v8s s[4][2];
    #pragma unroll
    for(int nt=0;nt<4;nt++){
        s[nt][0] = *(const v8s*)(Sp + (nt*16+lanelow)*64 + quad*8);
        s[nt][1] = *(const v8s*)(Sp + (nt*16+lanelow)*64 + 32 + quad*8);
    }
    float g[2][4][4];
    float sq[2][4];
    const float* Lp = Larr + ((size_t)bh*NCH + c)*Q;
    #pragma unroll
    for(int rt=0;rt<2;rt++){
        float eL[4];
        #pragma unroll
        for(int r=0;r<4;r++) eL[r] = __expf(Lp[half*32 + rt*16 + quad*4 + r]);
        #pragma unroll
        for(int nt=0;nt<4;nt++){
            v4f acc = (v4f){0.f,0.f,0.f,0.f};
            acc = __builtin_amdgcn_mfma_f32_16x16x32_bf16(a[rt][0], s[nt][0], acc, 0,0,0);
            acc = __builtin_amdgcn_mfma_f32_16x16x32_bf16(a[rt][1], s[nt][1], acc, 0,0,0);
            int col = h*HEADDIM + nt*16 + lanelow;
            #pragma unroll
            for(int r=0;r<4;r++){
                int i = half*32 + rt*16 + quad*4 + r;
                size_t tok = (size_t)b*SEQLEN + c*Q + i;
                float yv = acc[r]*eL[r] + bf2f(yw16[tok*DINNER + col]);
                float z  = bf2f(zxb[tok*DINPROJ + col]);
                float gg = yv * (z/(1.f+__expf(-z)));
                g[rt][nt][r] = gg;
                sq[rt][r] = (nt==0 ? gg*gg : sq[rt][r] + gg*gg);
            }
        }
    }
    #pragma unroll
    for(int rt=0;rt<2;rt++)
        #pragma unroll
        for(int r=0;r<4;r++){
            float v = sq[rt][r];
            #pragma unroll
            for(int m=1;m<16;m<<=1) v += __shfl_xor(v, m);
            sq[rt][r] = v;
        }
    if(lanelow==0){
        #pragma unroll
        for(int rt=0;rt<2;rt++)
            #pragma unroll
            for(int r=0;r<4;r++)
                wsum[h][rt*16 + quad*4 + r] = sq[rt][r];
    }
    __syncthreads();
    if(t < 32){
        float tot = 0.f;
        #pragma unroll
        for(int hh=0;hh<8;hh++) tot += wsum[hh][t];
        rstdS[t] = rsqrtf(tot*(1.f/512.f) + 1e-5f);
    }
    __syncthreads();
    #pragma unroll
    for(int rt=0;rt<2;rt++){
        #pragma unroll
        for(int nt=0;nt<4;nt++){
            int col = h*HEADDIM + nt*16 + lanelow;
            float rw = rms_w[col];
            #pragma unroll
            for(int r=0;r<4;r++){
                int i = rt*16 + quad*4 + r;
                Gb[((size_t)b*SEQLEN + c*Q + half*32 + i)*DINNER + col] = f2bf(g[rt][nt][r] * rstdS[i] * rw);
            }
        }
    }
}

extern "C" void kernel_launch(void* const* d_in, const int* in_sizes, int n_in,
                              void* d_out, int out_size, void* d_ws, size_t ws_size,
                              hipStream_t stream) {
    const float* hid     = (const float*)d_in[0];
    const float* norm_w  = (const float*)d_in[1];
    const float* norm_b  = (const float*)d_in[2];
    const float* Win     = (const float*)d_in[3];
    const float* conv_w  = (const float*)d_in[4];
    const float* conv_b  = (const float*)d_in[5];
    const float* dt_bias = (const float*)d_in[6];
    const float* A_log   = (const float*)d_in[7];
    const float* D_param = (const float*)d_in[8];
    const float* rms_w   = (const float*)d_in[9];
    const float* Wout    = (const float*)d_in[10];

    float* ws = (float*)d_ws;
    float* contrib = ws;                                          // 16*32*4096 f
    float* Larr    = contrib + (size_t)16*NCH*4096;               // 32768 f
    float* decayA  = Larr + (size_t)16*NCH*Q;                     // 512 f
    unsigned short* zxb  = (unsigned short*)(decayA + 512);       // 4096*1160
    unsigned short* yw16 = zxb + (size_t)NTOK*DINPROJ;            // 4096*512
    unsigned short* Sb   = yw16 + (size_t)NTOK*DINNER;            // 16*32*4096
    unsigned short* Ccv  = Sb + (size_t)16*NCH*4096;              // 2*32*4096
    unsigned short* Xb   = Ccv + (size_t)BATCH*NCH*4096;          // 4096*256
    unsigned short* Gb   = Xb + (size_t)NTOK*DMODEL;              // 4096*512
    unsigned short* Wti  = Gb + (size_t)NTOK*DINNER;              // 1216*256
    unsigned short* Wto  = Wti + (size_t)NPAD_IN*DMODEL;          // 256*512

    float* out = (float*)d_out;
    float* res = out + (size_t)NTOK*DMODEL;

    k_prep<<<256 + NPAD_IN/4 + DMODEL/4, 256, 0, stream>>>(hid, norm_w, norm_b, Win, Wout, res, Xb, Wti, Wto);
    k_gemm<1><<<dim3(NTOK/128, NPAD_IN/64), 256, 0, stream>>>(Xb, Wti, nullptr, zxb, DMODEL, DINPROJ);
    k_chunk1<<<BATCH*NHEADS*NCH, 256, 0, stream>>>(zxb, conv_w, conv_b, dt_bias, A_log, D_param,
                                                   yw16, contrib, Larr, decayA, Ccv);
    k_chunk2<<<256, 256, 0, stream>>>(contrib, decayA, Sb);
    k_tail<<<BATCH*NCH*2, 512, 0, stream>>>(Ccv, Sb, Larr, yw16, zxb, rms_w, Gb);
    k_gemm<0><<<dim3(NTOK/128, DMODEL/64), 256, 0, stream>>>(Gb, Wto, out, nullptr, DINNER, DMODEL);
}